// Round 1
// baseline (454.454 us; speedup 1.0000x reference)
//
#include <hip/hip_runtime.h>

// Local 3x3 variance (zero-padded, stride 1, divisor 9) over (8,32,512,512) fp32.
// out = boxsum(x^2)/9 - (boxsum(x)/9)^2
//
// One wave (64 lanes) handles a 256-col x 32-row tile; 4 waves per 256-thread
// block (independent row tiles). Lane owns 4 consecutive columns (float4).
// Column halo via __shfl; strip-edge lanes load one scalar. Zero padding is
// implemented by SKIPPING the load for out-of-range rows (wave-uniform branch)
// instead of per-row mask multiplies. Depth-1 software prefetch so each row's
// load is in flight during the previous row's compute.
//
// TH=32 (vs 16): halo read overhead (TH+2)/TH drops 12.5% -> 6.25%. Registers
// are unchanged (3-row rolling window), only the trip count grows.

#define IMG_H 512
#define IMG_W 512
#define TH 32   // output rows per wave

typedef float vfloat4 __attribute__((ext_vector_type(4)));  // native vec for nontemporal store

__global__ __launch_bounds__(256, 6) void var3x3_kernel(const float* __restrict__ x,
                                                        float* __restrict__ out) {
    const int tid   = threadIdx.x;
    const int lane  = tid & 63;
    const int wavei = tid >> 6;         // 0..3
    const int ws    = blockIdx.x;       // 0..1   (256-wide strips)
    const int hc    = blockIdx.y;       // 0..3   (128-row chunks)
    const int plane = blockIdx.z;       // 0..255 (b*c)

    const float* __restrict__ px = x   + (size_t)plane * (IMG_H * IMG_W);
    float*       __restrict__ po = out + (size_t)plane * (IMG_H * IMG_W);

    const int w0 = ws * 256 + lane * 4;     // first of this lane's 4 columns
    const int r0 = hc * 128 + wavei * TH;   // first output row of this wave

    const bool haveL = (w0 > 0);            // lane 0 of strip 1 needs scalar halo
    const bool haveR = (w0 + 4 < IMG_W);    // lane 63 of strip 0 needs scalar halo
    const float inv9 = 1.0f / 9.0f;

    float4 rsA = {0,0,0,0}, rsB = {0,0,0,0};   // rolling row-sums of x
    float4 rqA = {0,0,0,0}, rqB = {0,0,0,0};   // rolling row-sums of x^2

    // ---- prefetch input row h = r0-1 (zero if above the image) ----
    float4 vn = {0,0,0,0};
    float lnv = 0.f, rnv = 0.f;
    if (r0 > 0) {                       // wave-uniform
        const float* p = px + (size_t)(r0 - 1) * IMG_W;
        vn = *reinterpret_cast<const float4*>(p + w0);
        if (lane == 0 && haveL)  lnv = p[w0 - 1];
        if (lane == 63 && haveR) rnv = p[w0 + 4];
    }

    // iteration i consumes input row h = r0-1+i; emits output row r0+i-2
    #pragma unroll 3
    for (int i = 0; i < TH + 2; ++i) {
        float4 v = vn;
        float  lv = lnv, rv = rnv;

        if (i < TH + 1) {               // wave-uniform; prefetch input row r0+i
            const int h = r0 + i;       // never < 0 here
            lnv = 0.f; rnv = 0.f;
            if (h < IMG_H) {            // wave-uniform; skip-load == zero pad
                const float* p = px + (size_t)h * IMG_W;
                vn = *reinterpret_cast<const float4*>(p + w0);
                if (lane == 0 && haveL)  lnv = p[w0 - 1];
                if (lane == 63 && haveR) rnv = p[w0 + 4];
            } else {
                vn = {0,0,0,0};
            }
        }

        // column halo from neighbor lanes
        const float fu = __shfl_up(v.w, 1);
        const float fd = __shfl_down(v.x, 1);
        const float left  = (lane == 0)  ? lv : fu;
        const float right = (lane == 63) ? rv : fd;

        // 3-wide horizontal sums for this row
        float4 rsC, rqC;
        rsC.x = left + v.x + v.y;
        rsC.y = v.x  + v.y + v.z;
        rsC.z = v.y  + v.z + v.w;
        rsC.w = v.z  + v.w + right;
        const float l2 = left*left, a2 = v.x*v.x, b2 = v.y*v.y;
        const float c2 = v.z*v.z,  d2 = v.w*v.w, r2 = right*right;
        rqC.x = l2 + a2 + b2;
        rqC.y = a2 + b2 + c2;
        rqC.z = b2 + c2 + d2;
        rqC.w = c2 + d2 + r2;

        if (i >= 2) {
            const int ho = r0 + i - 2;
            vfloat4 o;
            { const float s = rsA.x+rsB.x+rsC.x, q = rqA.x+rqB.x+rqC.x, mm = s*inv9; o.x = q*inv9 - mm*mm; }
            { const float s = rsA.y+rsB.y+rsC.y, q = rqA.y+rqB.y+rqC.y, mm = s*inv9; o.y = q*inv9 - mm*mm; }
            { const float s = rsA.z+rsB.z+rsC.z, q = rqA.z+rqB.z+rqC.z, mm = s*inv9; o.z = q*inv9 - mm*mm; }
            { const float s = rsA.w+rsB.w+rsC.w, q = rqA.w+rqB.w+rqC.w, mm = s*inv9; o.w = q*inv9 - mm*mm; }
            __builtin_nontemporal_store(o, reinterpret_cast<vfloat4*>(po + (size_t)ho * IMG_W + w0));
        }
        rsA = rsB; rsB = rsC;
        rqA = rqB; rqB = rqC;
    }
}

extern "C" void kernel_launch(void* const* d_in, const int* in_sizes, int n_in,
                              void* d_out, int out_size, void* d_ws, size_t ws_size,
                              hipStream_t stream) {
    const float* x = (const float*)d_in[0];
    float* out = (float*)d_out;
    dim3 grid(2, 4, 256);   // w-strips, 128-row chunks, planes (8*32)
    dim3 block(256);        // 4 independent waves, each a 256x32 tile
    var3x3_kernel<<<grid, block, 0, stream>>>(x, out);
}

// Round 2
// 431.852 us; speedup vs baseline: 1.0523x; 1.0523x over previous
//
#include <hip/hip_runtime.h>

// Local 3x3 variance (zero-padded, stride 1, divisor 9) over (8,32,512,512) fp32.
// out = boxsum(x^2)/9 - (boxsum(x)/9)^2
//
// One wave (64 lanes) = 256-col x 16-row tile; 4 waves/block (independent row
// tiles); grid (2 strips, 8 chunks, 256 planes) = 4096 blocks = 16/CU.
//
// Latency-tolerance redesign (round 2):
//  - NO conditional loads, NO shfl: every lane loads its own left/right halo
//    scalar at a clamped column address (same cache lines as the float4 load,
//    L1-resident). Zero padding = clamped row pointer + 0/1 mask multiply.
//    Loop body is branch-free and exec-uniform -> precise counted vmcnt waits,
//    stores never enter the critical path.
//  - Depth-3 row prefetch (~3 KB in flight per wave) with the 18-iteration
//    loop fully unrolled so pipeline rotation renames away (no scratch).

#define IMG_H 512
#define IMG_W 512
#define TH 16   // output rows per wave
#define PF 3    // row prefetch depth

typedef float vfloat4 __attribute__((ext_vector_type(4)));  // for nontemporal store

__global__ __launch_bounds__(256, 6) void var3x3_kernel(const float* __restrict__ x,
                                                        float* __restrict__ out) {
    const int tid   = threadIdx.x;
    const int lane  = tid & 63;
    const int wavei = tid >> 6;         // 0..3
    const int ws    = blockIdx.x;       // 0..1   (256-wide strips)
    const int hc    = blockIdx.y;       // 0..7   (64-row chunks)
    const int plane = blockIdx.z;       // 0..255 (b*c)

    const float* __restrict__ px = x   + (size_t)plane * (IMG_H * IMG_W);
    float*       __restrict__ po = out + (size_t)plane * (IMG_H * IMG_W);

    const int w0 = ws * 256 + lane * 4;     // first of this lane's 4 columns
    const int r0 = hc * 64 + wavei * TH;    // first output row of this wave

    // clamped halo columns + their validity (0 exactly at the image edges)
    const int   cl = (w0 == 0) ? 0 : (w0 - 1);
    const int   cr = (w0 + 4 >= IMG_W) ? (IMG_W - 1) : (w0 + 4);
    const float mL = (w0 == 0) ? 0.f : 1.f;
    const float mR = (w0 + 4 >= IMG_W) ? 0.f : 1.f;
    const float inv9 = 1.0f / 9.0f;

    // load input row r0-1+j (clamped) into the pipeline slot
#define LOADROW(V, L, R, M, j) do {                                          \
        const int h_  = r0 - 1 + (j);                                        \
        const int hcl = h_ < 0 ? 0 : (h_ > IMG_H - 1 ? IMG_H - 1 : h_);      \
        const float* p_ = px + (size_t)hcl * IMG_W;                          \
        V = *reinterpret_cast<const float4*>(p_ + w0);                       \
        L = p_[cl];                                                          \
        R = p_[cr];                                                          \
        M = (h_ >= 0 && h_ < IMG_H) ? 1.0f : 0.0f;                           \
    } while (0)

    // 3-row pipeline
    float4 va, vb, vc;
    float  la, lb, lc, ra, rb, rc, ma, mb, mc;
    LOADROW(va, la, ra, ma, 0);
    LOADROW(vb, lb, rb, mb, 1);
    LOADROW(vc, lc, rc, mc, 2);

    float4 rsA = {0,0,0,0}, rsB = {0,0,0,0};   // rolling horizontal sums of x
    float4 rqA = {0,0,0,0}, rqB = {0,0,0,0};   // rolling horizontal sums of x^2

    // iteration i consumes input row r0-1+i; emits output row r0+i-2 for i>=2
    #pragma unroll
    for (int i = 0; i < TH + 2; ++i) {
        float4 v = va;
        float  lv = la * mL, rv = ra * mR;
        const float m = ma;

        // rotate pipeline (renamed away by full unroll)
        va = vb; la = lb; ra = rb; ma = mb;
        vb = vc; lb = lc; rb = rc; mb = mc;
        if (i + PF < TH + 2) {             // compile-time after unroll
            LOADROW(vc, lc, rc, mc, i + PF);
        }

        // zero-padding mask
        v.x *= m; v.y *= m; v.z *= m; v.w *= m; lv *= m; rv *= m;

        // 3-wide horizontal sums for this row
        float4 rsC, rqC;
        rsC.x = lv  + v.x + v.y;
        rsC.y = v.x + v.y + v.z;
        rsC.z = v.y + v.z + v.w;
        rsC.w = v.z + v.w + rv;
        const float l2 = lv*lv,  a2 = v.x*v.x, b2 = v.y*v.y;
        const float c2 = v.z*v.z, d2 = v.w*v.w, r2 = rv*rv;
        rqC.x = l2 + a2 + b2;
        rqC.y = a2 + b2 + c2;
        rqC.z = b2 + c2 + d2;
        rqC.w = c2 + d2 + r2;

        if (i >= 2) {                      // compile-time after unroll
            const int ho = r0 + i - 2;
            vfloat4 o;
            { const float s = rsA.x+rsB.x+rsC.x, q = rqA.x+rqB.x+rqC.x, mm = s*inv9; o.x = q*inv9 - mm*mm; }
            { const float s = rsA.y+rsB.y+rsC.y, q = rqA.y+rqB.y+rqC.y, mm = s*inv9; o.y = q*inv9 - mm*mm; }
            { const float s = rsA.z+rsB.z+rsC.z, q = rqA.z+rqB.z+rqC.z, mm = s*inv9; o.z = q*inv9 - mm*mm; }
            { const float s = rsA.w+rsB.w+rsC.w, q = rqA.w+rqB.w+rqC.w, mm = s*inv9; o.w = q*inv9 - mm*mm; }
            __builtin_nontemporal_store(o, reinterpret_cast<vfloat4*>(po + (size_t)ho * IMG_W + w0));
        }
        rsA = rsB; rsB = rsC;
        rqA = rqB; rqB = rqC;
    }
#undef LOADROW
}

extern "C" void kernel_launch(void* const* d_in, const int* in_sizes, int n_in,
                              void* d_out, int out_size, void* d_ws, size_t ws_size,
                              hipStream_t stream) {
    const float* x = (const float*)d_in[0];
    float* out = (float*)d_out;
    dim3 grid(2, 8, 256);   // w-strips, 64-row chunks, planes (8*32)
    dim3 block(256);        // 4 independent waves, each a 256x16 tile
    var3x3_kernel<<<grid, block, 0, stream>>>(x, out);
}